// Round 2
// baseline (5294.597 us; speedup 1.0000x reference)
//
#include <hip/hip_runtime.h>

// Problem constants (from reference setup_inputs)
#define T_TOK   32768
#define N_SLOTS 128
#define D_DIM   4096
#define B_DIM   4

// sums kernel tiling
#define W_SLICE 128                       // D columns per block
#define C_TOK   2048                      // tokens per block
#define MAIN_THREADS 1024
#define N_SLICES (D_DIM / W_SLICE)        // 32
#define N_CHUNKS (T_TOK / C_TOK)          // 16
#define ROWS_PER_ITER (MAIN_THREADS / (W_SLICE / 4))  // 32 token rows per block-iter

typedef unsigned long long u64;

// ws layout
#define SUMS_BYTES   ((size_t)N_SLOTS * D_DIM * sizeof(float))   // 2 MiB
#define COUNTS_OFF   SUMS_BYTES
#define PACKED_OFF   (SUMS_BYTES + 512)                          // 128*4 counts, pad to 512
#define ZERO_BYTES   PACKED_OFF                                  // zero sums+counts each call

// Native LDS float atomic: workgroup scope + relaxed => ds_add_f32 (no return).
#define LDS_FADD(p, v) (void)__hip_atomic_fetch_add((p), (v), __ATOMIC_RELAXED, __HIP_MEMORY_SCOPE_WORKGROUP)

// ---------------------------------------------------------------------------
// Kernel 1: dedup slot indices per token -> packed u64 (byte = slot or 0xFF),
// and accumulate counts[n] (distinct-per-token semantics).
// ---------------------------------------------------------------------------
__global__ __launch_bounds__(256) void prep_kernel(const int* __restrict__ sidx,
                                                   u64* __restrict__ packed,
                                                   int* __restrict__ counts) {
  __shared__ int cnt[N_SLOTS];
  const int tid = threadIdx.x;
  if (tid < N_SLOTS) cnt[tid] = 0;
  __syncthreads();

  const int t = blockIdx.x * 256 + tid;   // grid exactly covers T_TOK
  const int4 a = ((const int4*)sidx)[2 * t];
  const int4 b = ((const int4*)sidx)[2 * t + 1];
  int idx[8] = {a.x, a.y, a.z, a.w, b.x, b.y, b.z, b.w};

  u64 pk = 0;
  #pragma unroll
  for (int k = 0; k < 8; ++k) {
    int n = idx[k];
    bool dup = false;
    #pragma unroll
    for (int j = 0; j < 8; ++j)
      if (j < k) dup |= (idx[j] == n);
    u64 byte = (dup || (unsigned)n >= (unsigned)N_SLOTS) ? 0xFFull : (u64)(unsigned)n;
    pk |= byte << (8 * k);
    if (byte != 0xFFull) atomicAdd(&cnt[n], 1);
  }
  packed[t] = pk;

  __syncthreads();
  if (tid < N_SLOTS && cnt[tid] > 0) atomicAdd(&counts[tid], cnt[tid]);
}

// ---------------------------------------------------------------------------
// Kernel 2: the 512 MB stream. Each block: one 128-wide D-slice x 2048 tokens.
// LDS acc row n stored transposed: word = n*128 + c*32 + col
// (c = float4 component, col = thread column). ds_add_f32 banks = col -> 2-way.
// Row 128 is a trash row for dup/invalid slots (branch-free inner loop).
// ---------------------------------------------------------------------------
__global__ __launch_bounds__(MAIN_THREADS) void sums_kernel(const float* __restrict__ hidden,
                                                            const u64* __restrict__ packed,
                                                            float* __restrict__ sums) {
  __shared__ float acc[(N_SLOTS + 1) * W_SLICE];   // 66 KiB (incl. trash row)
  const int tid = threadIdx.x;
  #pragma unroll
  for (int i = 0; i < (N_SLOTS * W_SLICE) / MAIN_THREADS; ++i)
    acc[i * MAIN_THREADS + tid] = 0.0f;            // trash row needs no init
  __syncthreads();

  const int slice = blockIdx.x & (N_SLICES - 1);
  const int chunk = blockIdx.x / N_SLICES;
  const int d0 = slice * W_SLICE;
  const int col = tid & 31;      // float4 column within slice
  const int r   = tid >> 5;      // token row within iter group (0..31)
  const float4* __restrict__ h4 = (const float4*)hidden;
  const size_t rowStride4 = D_DIM / 4;

  int t = chunk * C_TOK + r;
  #pragma unroll 2
  for (int it = 0; it < C_TOK / ROWS_PER_ITER; ++it, t += ROWS_PER_ITER) {
    float4 h = h4[(size_t)t * rowStride4 + (d0 >> 2) + col];
    u64 pk = packed[t];
    #pragma unroll
    for (int k = 0; k < 8; ++k) {
      int n = (int)((pk >> (8 * k)) & 0xFF);
      n = n < N_SLOTS ? n : N_SLOTS;               // dups/invalid -> trash row
      const int base = (n << 7) + col;
      LDS_FADD(&acc[base],      h.x);
      LDS_FADD(&acc[base + 32], h.y);
      LDS_FADD(&acc[base + 64], h.z);
      LDS_FADD(&acc[base + 96], h.w);
    }
  }
  __syncthreads();

  // Flush LDS partial sums (rows 0..127 only) to global ws sums via f32 atomics.
  #pragma unroll
  for (int i = 0; i < (N_SLOTS * W_SLICE) / MAIN_THREADS; ++i) {
    int w = i * MAIN_THREADS + tid;
    int n = w >> 7;
    int p = w & 127;
    int x = ((p & 31) << 2) | (p >> 5);   // logical column within slice
    unsafeAtomicAdd(&sums[(size_t)n * D_DIM + d0 + x], acc[w]);
  }
}

// ---------------------------------------------------------------------------
// Kernel 3: out = memory, with row batch_idx blended:
//   counts>0 ? 0.1*sums/counts + 0.9*cur : cur
// ---------------------------------------------------------------------------
__global__ __launch_bounds__(256) void final_kernel(const float* __restrict__ memory,
                                                    const float* __restrict__ sums,
                                                    const int* __restrict__ counts,
                                                    const int* __restrict__ bidx_p,
                                                    float* __restrict__ out) {
  const size_t i = (size_t)blockIdx.x * 256 + threadIdx.x;   // float4 index
  float4 v = ((const float4*)memory)[i];
  const size_t rowLen4 = (size_t)N_SLOTS * (D_DIM / 4);
  const size_t rowStart = (size_t)(*bidx_p) * rowLen4;
  if (i >= rowStart && i < rowStart + rowLen4) {
    const size_t rel = i - rowStart;
    const int n  = (int)(rel / (D_DIM / 4));
    const int d4 = (int)(rel % (D_DIM / 4));
    const int c = counts[n];
    if (c > 0) {
      float4 s = ((const float4*)sums)[(size_t)n * (D_DIM / 4) + d4];
      const float w = 0.1f / (float)c;
      v.x = s.x * w + 0.9f * v.x;
      v.y = s.y * w + 0.9f * v.y;
      v.z = s.z * w + 0.9f * v.z;
      v.w = s.w * w + 0.9f * v.w;
    }
  }
  ((float4*)out)[i] = v;
}

extern "C" void kernel_launch(void* const* d_in, const int* in_sizes, int n_in,
                              void* d_out, int out_size, void* d_ws, size_t ws_size,
                              hipStream_t stream) {
  const float* memory = (const float*)d_in[0];
  const float* hidden = (const float*)d_in[1];
  const int*   sidx   = (const int*)d_in[2];
  const int*   bidx   = (const int*)d_in[3];
  float* out = (float*)d_out;

  char* ws = (char*)d_ws;
  float* sums   = (float*)ws;
  int*   counts = (int*)(ws + COUNTS_OFF);
  u64*   packed = (u64*)(ws + PACKED_OFF);

  // zero sums + counts (packed is fully overwritten by prep)
  hipMemsetAsync(ws, 0, ZERO_BYTES, stream);

  prep_kernel<<<T_TOK / 256, 256, 0, stream>>>(sidx, packed, counts);

  sums_kernel<<<N_CHUNKS * N_SLICES, MAIN_THREADS, 0, stream>>>(hidden, packed, sums);

  const int totalVec4 = B_DIM * N_SLOTS * (D_DIM / 4);   // 524288
  final_kernel<<<totalVec4 / 256, 256, 0, stream>>>(memory, sums, counts, bidx, out);
}

// Round 3
// 151.873 us; speedup vs baseline: 34.8619x; 34.8619x over previous
//
#include <hip/hip_runtime.h>

// Problem constants (from reference setup_inputs)
#define T_TOK   32768
#define N_SLOTS 128
#define D_DIM   4096
#define B_DIM   4

// GEMM tiling: sums[128, 4096] = m^T[128, T] @ h[T, 4096]
#define NCHUNK  16                  // split-T
#define CTOK    (T_TOK / NCHUNK)    // 2048 tokens per block
#define KB      64                  // tokens per LDS tile (MFMA K per tile)
#define NT      (CTOK / KB)         // 32 tiles
#define WCOLS   128                 // D columns per block
#define NSLICE  (D_DIM / WCOLS)     // 32
#define THREADS 256                 // 4 waves

typedef __attribute__((ext_vector_type(8))) short short8;   // 8 bf16
typedef __attribute__((ext_vector_type(4))) float f32x4;

// ws layout
#define SUMS_BYTES ((size_t)N_SLOTS * D_DIM * 4)   // 2 MiB
#define COUNTS_OFF SUMS_BYTES
#define ZERO_BYTES (SUMS_BYTES + 512)

__device__ __forceinline__ unsigned short f2bf(float x) {  // RNE f32->bf16
  unsigned int u = __float_as_uint(x);
  return (unsigned short)((u + 0x7FFFu + ((u >> 16) & 1u)) >> 16);
}

// ---------------------------------------------------------------------------
// Kernel 1: counts[n] = number of tokens whose (deduped) top-K set contains n.
// ---------------------------------------------------------------------------
__global__ __launch_bounds__(256) void prep_kernel(const int* __restrict__ sidx,
                                                   int* __restrict__ counts) {
  __shared__ int cnt[N_SLOTS];
  const int tid = threadIdx.x;
  if (tid < N_SLOTS) cnt[tid] = 0;
  __syncthreads();

  const int t = blockIdx.x * 256 + tid;
  const int4 a = ((const int4*)sidx)[2 * t];
  const int4 b = ((const int4*)sidx)[2 * t + 1];
  int idx[8] = {a.x, a.y, a.z, a.w, b.x, b.y, b.z, b.w};

  #pragma unroll
  for (int k = 0; k < 8; ++k) {
    int n = idx[k];
    bool dup = false;
    #pragma unroll
    for (int j = 0; j < 8; ++j)
      if (j < k) dup |= (idx[j] == n);
    if (!dup && (unsigned)n < (unsigned)N_SLOTS) atomicAdd(&cnt[n], 1);
  }
  __syncthreads();
  if (tid < N_SLOTS && cnt[tid] > 0) atomicAdd(&counts[tid], cnt[tid]);
}

// ---------------------------------------------------------------------------
// Kernel 2: MFMA GEMM over the 512 MB h stream. No atomics in the hot loop.
// LDS layouts (bf16 elem index, XOR-swizzled so k-groups of 8 stay contiguous):
//   h tile: elem = col*64 + (k ^ ((col&7)<<3))   (stored as b32 k-pair words)
//   m tile: elem =   n*64 + (k ^ ((n  &7)<<3))
// m is built by zero + scatter-write of bf16 1.0 (dup writes benign => dedup free).
// ---------------------------------------------------------------------------
__global__ __launch_bounds__(THREADS, 2) void sums_kernel(
    const float* __restrict__ hidden, const int* __restrict__ sidx,
    float* __restrict__ sums) {
  __shared__ unsigned int   h_w[2][4096];   // 16 KiB per buffer
  __shared__ unsigned short m_u[2][8192];   // 16 KiB per buffer

  const int tid = threadIdx.x;
  const int slice = blockIdx.x & (NSLICE - 1);
  const int chunk = blockIdx.x / NSLICE;
  const int d0 = slice * WCOLS;
  const int cb = chunk * CTOK;

  // staging coords: thread owns token-pair kp (k=2kp,2kp+1) x 16 cols
  const int kp = tid & 31;
  const int cg = tid >> 5;   // col group (16 cols each)

  // compute coords
  const int lane = tid & 63;
  const int wv   = tid >> 6;   // wave 0..3 -> N-tiles {2wv, 2wv+1}
  const int l15  = lane & 15;
  const int lk   = lane >> 4;  // k-group 0..3

  f32x4 acc[8][2];
  #pragma unroll
  for (int i = 0; i < 8; ++i)
    #pragma unroll
    for (int j = 0; j < 2; ++j)
      acc[i][j] = (f32x4){0.f, 0.f, 0.f, 0.f};

  float4 fa[4], fb[4];   // prefetched h: token 2kp and 2kp+1, 16 cols each
  int s0, s1;            // prefetched slot indices (flat j = tid, tid+256)

  {  // prologue: loads for tile 0
    const float* hp = hidden + (size_t)(cb + 2 * kp) * D_DIM + d0 + cg * 16;
    #pragma unroll
    for (int q = 0; q < 4; ++q) {
      fa[q] = ((const float4*)hp)[q];
      fb[q] = ((const float4*)(hp + D_DIM))[q];
    }
    s0 = sidx[cb * 8 + tid];
    s1 = sidx[cb * 8 + 256 + tid];
  }

  for (int t = 0; t < NT; ++t) {
    const int b = t & 1;

    // ---- stage h tile: cvt f32->bf16, pack (k,k+1), b32 write (2-way free) --
    #pragma unroll
    for (int q = 0; q < 4; ++q) {
      const int colbase = cg * 16 + q * 4;
      const float ax[4] = {fa[q].x, fa[q].y, fa[q].z, fa[q].w};
      const float bx[4] = {fb[q].x, fb[q].y, fb[q].z, fb[q].w};
      #pragma unroll
      for (int c = 0; c < 4; ++c) {
        const int col = colbase + c;
        const unsigned int pack =
            (unsigned int)f2bf(ax[c]) | ((unsigned int)f2bf(bx[c]) << 16);
        h_w[b][col * 32 + (kp ^ ((col & 7) << 2))] = pack;
      }
    }
    // ---- zero m tile ----
    {
      uint4* mz = (uint4*)m_u[b];
      const uint4 z = make_uint4(0, 0, 0, 0);
      #pragma unroll
      for (int i = 0; i < 4; ++i) mz[i * THREADS + tid] = z;
    }
    __syncthreads();   // zero visible before scatter

    // ---- scatter m: write bf16 1.0 at (n, token) ----
    {
      const int n0 = s0 & (N_SLOTS - 1);
      const int t0 = tid >> 3;
      m_u[b][n0 * 64 + (t0 ^ ((n0 & 7) << 3))] = 0x3F80;
      const int n1 = s1 & (N_SLOTS - 1);
      const int t1 = (tid + 256) >> 3;
      m_u[b][n1 * 64 + (t1 ^ ((n1 & 7) << 3))] = 0x3F80;
    }

    // ---- issue next tile's global loads ----
    if (t + 1 < NT) {
      const int tb = cb + (t + 1) * KB;
      const float* hp = hidden + (size_t)(tb + 2 * kp) * D_DIM + d0 + cg * 16;
      #pragma unroll
      for (int q = 0; q < 4; ++q) {
        fa[q] = ((const float4*)hp)[q];
        fb[q] = ((const float4*)(hp + D_DIM))[q];
      }
      s0 = sidx[tb * 8 + tid];
      s1 = sidx[tb * 8 + 256 + tid];
    }
    __syncthreads();   // tile staged before compute

    // ---- MFMA: acc += m^T(tile) @ h(tile) ----
    {
      const unsigned short* mb = m_u[b];
      const unsigned short* hb = (const unsigned short*)h_w[b];
      #pragma unroll
      for (int ks = 0; ks < 2; ++ks) {
        const int kbase = ks * 32 + lk * 8;
        const int col0 = (wv * 2) * 16 + l15;
        const int col1 = (wv * 2 + 1) * 16 + l15;
        const short8 bf0 = *(const short8*)&hb[col0 * 64 + (kbase ^ ((col0 & 7) << 3))];
        const short8 bf1 = *(const short8*)&hb[col1 * 64 + (kbase ^ ((col1 & 7) << 3))];
        #pragma unroll
        for (int mt = 0; mt < 8; ++mt) {
          const int row = mt * 16 + l15;
          const short8 af = *(const short8*)&mb[row * 64 + (kbase ^ ((row & 7) << 3))];
          acc[mt][0] = __builtin_amdgcn_mfma_f32_16x16x32_bf16(af, bf0, acc[mt][0], 0, 0, 0);
          acc[mt][1] = __builtin_amdgcn_mfma_f32_16x16x32_bf16(af, bf1, acc[mt][1], 0, 0, 0);
        }
      }
    }
  }

  // ---- flush partials: C/D layout col=lane&15, row=(lane>>4)*4+reg ----
  #pragma unroll
  for (int mt = 0; mt < 8; ++mt)
    #pragma unroll
    for (int j = 0; j < 2; ++j)
      #pragma unroll
      for (int r = 0; r < 4; ++r) {
        const int row = mt * 16 + lk * 4 + r;
        const int col = d0 + (wv * 2 + j) * 16 + l15;
        unsafeAtomicAdd(&sums[(size_t)row * D_DIM + col], acc[mt][j][r]);
      }
}

// ---------------------------------------------------------------------------
// Kernel 3: out = memory, with row batch_idx blended.
// ---------------------------------------------------------------------------
__global__ __launch_bounds__(256) void final_kernel(const float* __restrict__ memory,
                                                    const float* __restrict__ sums,
                                                    const int* __restrict__ counts,
                                                    const int* __restrict__ bidx_p,
                                                    float* __restrict__ out) {
  const size_t i = (size_t)blockIdx.x * 256 + threadIdx.x;   // float4 index
  float4 v = ((const float4*)memory)[i];
  const size_t rowLen4 = (size_t)N_SLOTS * (D_DIM / 4);
  const size_t rowStart = (size_t)(*bidx_p) * rowLen4;
  if (i >= rowStart && i < rowStart + rowLen4) {
    const size_t rel = i - rowStart;
    const int n  = (int)(rel / (D_DIM / 4));
    const int d4 = (int)(rel % (D_DIM / 4));
    const int c = counts[n];
    if (c > 0) {
      float4 s = ((const float4*)sums)[(size_t)n * (D_DIM / 4) + d4];
      const float w = 0.1f / (float)c;
      v.x = s.x * w + 0.9f * v.x;
      v.y = s.y * w + 0.9f * v.y;
      v.z = s.z * w + 0.9f * v.z;
      v.w = s.w * w + 0.9f * v.w;
    }
  }
  ((float4*)out)[i] = v;
}

extern "C" void kernel_launch(void* const* d_in, const int* in_sizes, int n_in,
                              void* d_out, int out_size, void* d_ws, size_t ws_size,
                              hipStream_t stream) {
  const float* memory = (const float*)d_in[0];
  const float* hidden = (const float*)d_in[1];
  const int*   sidx   = (const int*)d_in[2];
  const int*   bidx   = (const int*)d_in[3];
  float* out = (float*)d_out;

  char* ws = (char*)d_ws;
  float* sums   = (float*)ws;
  int*   counts = (int*)(ws + COUNTS_OFF);

  hipMemsetAsync(ws, 0, ZERO_BYTES, stream);

  prep_kernel<<<T_TOK / 256, 256, 0, stream>>>(sidx, counts);

  sums_kernel<<<NCHUNK * NSLICE, THREADS, 0, stream>>>(hidden, sidx, sums);

  const int totalVec4 = B_DIM * N_SLOTS * (D_DIM / 4);   // 524288
  final_kernel<<<totalVec4 / 256, 256, 0, stream>>>(memory, sums, counts, bidx, out);
}

// Round 4
// 131.989 us; speedup vs baseline: 40.1138x; 1.1506x over previous
//
#include <hip/hip_runtime.h>

// Problem constants (from reference setup_inputs)
#define T_TOK   32768
#define N_SLOTS 128
#define D_DIM   4096
#define B_DIM   4

// GEMM tiling: sums[128, 4096] = m^T[128, T] @ h[T, 4096]
#define NCHUNK  16                  // split-T
#define CTOK    (T_TOK / NCHUNK)    // 2048 tokens per block
#define KB      64                  // tokens per LDS tile (MFMA K per tile)
#define NT      (CTOK / KB)         // 32 tiles
#define WCOLS   128                 // D columns per block
#define NSLICE  (D_DIM / WCOLS)     // 32
#define THREADS 256                 // 4 waves

typedef __attribute__((ext_vector_type(8))) short short8;   // 8 bf16
typedef __attribute__((ext_vector_type(4))) float f32x4;

// ws layout: partial[NCHUNK][128][4096] f32 (32 MiB), then counts
#define PARTIAL_BYTES ((size_t)NCHUNK * N_SLOTS * D_DIM * 4)
#define COUNTS_OFF    PARTIAL_BYTES

__device__ __forceinline__ unsigned short f2bf(float x) {  // RNE f32->bf16
  unsigned int u = __float_as_uint(x);
  return (unsigned short)((u + 0x7FFFu + ((u >> 16) & 1u)) >> 16);
}

// ---------------------------------------------------------------------------
// Kernel 1: counts[n] = number of tokens whose (deduped) top-K set contains n.
// ---------------------------------------------------------------------------
__global__ __launch_bounds__(256) void prep_kernel(const int* __restrict__ sidx,
                                                   int* __restrict__ counts) {
  __shared__ int cnt[N_SLOTS];
  const int tid = threadIdx.x;
  if (tid < N_SLOTS) cnt[tid] = 0;
  __syncthreads();

  const int t = blockIdx.x * 256 + tid;
  const int4 a = ((const int4*)sidx)[2 * t];
  const int4 b = ((const int4*)sidx)[2 * t + 1];
  int idx[8] = {a.x, a.y, a.z, a.w, b.x, b.y, b.z, b.w};

  #pragma unroll
  for (int k = 0; k < 8; ++k) {
    int n = idx[k];
    bool dup = false;
    #pragma unroll
    for (int j = 0; j < 8; ++j)
      if (j < k) dup |= (idx[j] == n);
    if (!dup && (unsigned)n < (unsigned)N_SLOTS) atomicAdd(&cnt[n], 1);
  }
  __syncthreads();
  if (tid < N_SLOTS && cnt[tid] > 0) atomicAdd(&counts[tid], cnt[tid]);
}

// ---------------------------------------------------------------------------
// Kernel 2: MFMA GEMM over the 512 MB h stream. No atomics anywhere.
// LDS layouts (bf16 elem index, XOR-swizzled so k-groups of 8 stay contiguous):
//   h tile: elem = col*64 + (k ^ ((col&7)<<3))   (stored as b32 k-pair words)
//   m tile: elem =   n*64 + (k ^ ((n  &7)<<3))
// m is built by zero + scatter-write of bf16 1.0 (dup writes benign => dedup free).
// Each block stores its 128x128 f32 tile to partial[chunk] with plain stores;
// the 16-way chunk reduction is folded into final_kernel.
// ---------------------------------------------------------------------------
__global__ __launch_bounds__(THREADS, 2) void sums_kernel(
    const float* __restrict__ hidden, const int* __restrict__ sidx,
    float* __restrict__ partial) {
  __shared__ unsigned int   h_w[2][4096];   // 16 KiB per buffer
  __shared__ unsigned short m_u[2][8192];   // 16 KiB per buffer

  const int tid = threadIdx.x;
  const int slice = blockIdx.x & (NSLICE - 1);
  const int chunk = blockIdx.x / NSLICE;
  const int d0 = slice * WCOLS;
  const int cb = chunk * CTOK;

  // staging coords: thread owns token-pair kp (k=2kp,2kp+1) x 16 cols
  const int kp = tid & 31;
  const int cg = tid >> 5;   // col group (16 cols each)

  // compute coords
  const int lane = tid & 63;
  const int wv   = tid >> 6;   // wave 0..3 -> N-tiles {2wv, 2wv+1}
  const int l15  = lane & 15;
  const int lk   = lane >> 4;  // k-group 0..3

  f32x4 acc[8][2];
  #pragma unroll
  for (int i = 0; i < 8; ++i)
    #pragma unroll
    for (int j = 0; j < 2; ++j)
      acc[i][j] = (f32x4){0.f, 0.f, 0.f, 0.f};

  float4 fa[4], fb[4];   // prefetched h: token 2kp and 2kp+1, 16 cols each
  int s0, s1;            // prefetched slot indices (flat j = tid, tid+256)

  {  // prologue: loads for tile 0
    const float* hp = hidden + (size_t)(cb + 2 * kp) * D_DIM + d0 + cg * 16;
    #pragma unroll
    for (int q = 0; q < 4; ++q) {
      fa[q] = ((const float4*)hp)[q];
      fb[q] = ((const float4*)(hp + D_DIM))[q];
    }
    s0 = sidx[cb * 8 + tid];
    s1 = sidx[cb * 8 + 256 + tid];
  }

  for (int t = 0; t < NT; ++t) {
    const int b = t & 1;
    const int cs0 = s0, cs1 = s1;   // consume prefetched indices this tile

    // ---- stage h tile: cvt f32->bf16, pack (k,k+1), b32 write (2-way free) --
    #pragma unroll
    for (int q = 0; q < 4; ++q) {
      const int colbase = cg * 16 + q * 4;
      const float ax[4] = {fa[q].x, fa[q].y, fa[q].z, fa[q].w};
      const float bx[4] = {fb[q].x, fb[q].y, fb[q].z, fb[q].w};
      #pragma unroll
      for (int c = 0; c < 4; ++c) {
        const int col = colbase + c;
        const unsigned int pack =
            (unsigned int)f2bf(ax[c]) | ((unsigned int)f2bf(bx[c]) << 16);
        h_w[b][col * 32 + (kp ^ ((col & 7) << 2))] = pack;
      }
    }

    // ---- issue next tile's global loads (in flight across both barriers) ----
    if (t + 1 < NT) {
      const int tb = cb + (t + 1) * KB;
      const float* hp = hidden + (size_t)(tb + 2 * kp) * D_DIM + d0 + cg * 16;
      #pragma unroll
      for (int q = 0; q < 4; ++q) {
        fa[q] = ((const float4*)hp)[q];
        fb[q] = ((const float4*)(hp + D_DIM))[q];
      }
      s0 = sidx[tb * 8 + tid];
      s1 = sidx[tb * 8 + 256 + tid];
    }

    // ---- zero m tile ----
    {
      uint4* mz = (uint4*)m_u[b];
      const uint4 z = make_uint4(0, 0, 0, 0);
      #pragma unroll
      for (int i = 0; i < 4; ++i) mz[i * THREADS + tid] = z;
    }
    __syncthreads();   // zero visible before scatter

    // ---- scatter m: write bf16 1.0 at (n, token) ----
    {
      const int n0 = cs0 & (N_SLOTS - 1);
      const int t0 = tid >> 3;
      m_u[b][n0 * 64 + (t0 ^ ((n0 & 7) << 3))] = 0x3F80;
      const int n1 = cs1 & (N_SLOTS - 1);
      const int t1 = (tid + 256) >> 3;
      m_u[b][n1 * 64 + (t1 ^ ((n1 & 7) << 3))] = 0x3F80;
    }
    __syncthreads();   // tile staged before compute

    // ---- MFMA: acc += m^T(tile) @ h(tile) ----
    {
      const unsigned short* mb = m_u[b];
      const unsigned short* hb = (const unsigned short*)h_w[b];
      #pragma unroll
      for (int ks = 0; ks < 2; ++ks) {
        const int kbase = ks * 32 + lk * 8;
        const int col0 = (wv * 2) * 16 + l15;
        const int col1 = (wv * 2 + 1) * 16 + l15;
        const short8 bf0 = *(const short8*)&hb[col0 * 64 + (kbase ^ ((col0 & 7) << 3))];
        const short8 bf1 = *(const short8*)&hb[col1 * 64 + (kbase ^ ((col1 & 7) << 3))];
        #pragma unroll
        for (int mt = 0; mt < 8; ++mt) {
          const int row = mt * 16 + l15;
          const short8 af = *(const short8*)&mb[row * 64 + (kbase ^ ((row & 7) << 3))];
          acc[mt][0] = __builtin_amdgcn_mfma_f32_16x16x32_bf16(af, bf0, acc[mt][0], 0, 0, 0);
          acc[mt][1] = __builtin_amdgcn_mfma_f32_16x16x32_bf16(af, bf1, acc[mt][1], 0, 0, 0);
        }
      }
    }
  }

  // ---- flush: plain stores of this block's 128x128 tile into partial[chunk].
  //      C/D layout: col=lane&15, row=(lane>>4)*4+reg. Per store inst a wave
  //      covers 4 rows x 16 cols = 4x64B segments (full HBM-sector efficiency).
  float* pbase = partial + (size_t)chunk * N_SLOTS * D_DIM;
  #pragma unroll
  for (int mt = 0; mt < 8; ++mt)
    #pragma unroll
    for (int j = 0; j < 2; ++j) {
      const int col = d0 + (wv * 2 + j) * 16 + l15;
      #pragma unroll
      for (int r = 0; r < 4; ++r) {
        const int row = mt * 16 + lk * 4 + r;
        pbase[(size_t)row * D_DIM + col] = acc[mt][j][r];
      }
    }
}

// ---------------------------------------------------------------------------
// Kernel 3: out = memory, with row batch_idx blended:
//   counts>0 ? 0.1*(sum_c partial[c])/counts + 0.9*cur : cur
// ---------------------------------------------------------------------------
__global__ __launch_bounds__(256) void final_kernel(const float* __restrict__ memory,
                                                    const float* __restrict__ partial,
                                                    const int* __restrict__ counts,
                                                    const int* __restrict__ bidx_p,
                                                    float* __restrict__ out) {
  const size_t i = (size_t)blockIdx.x * 256 + threadIdx.x;   // float4 index
  float4 v = ((const float4*)memory)[i];
  const size_t rowLen4 = (size_t)N_SLOTS * (D_DIM / 4);
  const size_t rowStart = (size_t)(*bidx_p) * rowLen4;
  if (i >= rowStart && i < rowStart + rowLen4) {
    const size_t rel = i - rowStart;
    const int n  = (int)(rel / (D_DIM / 4));
    const int d4 = (int)(rel % (D_DIM / 4));
    const int c = counts[n];
    if (c > 0) {
      const float4* p4 = (const float4*)partial;
      float4 s = {0.f, 0.f, 0.f, 0.f};
      #pragma unroll
      for (int ch = 0; ch < NCHUNK; ++ch) {
        float4 p = p4[((size_t)ch * N_SLOTS + n) * (D_DIM / 4) + d4];
        s.x += p.x; s.y += p.y; s.z += p.z; s.w += p.w;
      }
      const float w = 0.1f / (float)c;
      v.x = s.x * w + 0.9f * v.x;
      v.y = s.y * w + 0.9f * v.y;
      v.z = s.z * w + 0.9f * v.z;
      v.w = s.w * w + 0.9f * v.w;
    }
  }
  ((float4*)out)[i] = v;
}

extern "C" void kernel_launch(void* const* d_in, const int* in_sizes, int n_in,
                              void* d_out, int out_size, void* d_ws, size_t ws_size,
                              hipStream_t stream) {
  const float* memory = (const float*)d_in[0];
  const float* hidden = (const float*)d_in[1];
  const int*   sidx   = (const int*)d_in[2];
  const int*   bidx   = (const int*)d_in[3];
  float* out = (float*)d_out;

  char* ws = (char*)d_ws;
  float* partial = (float*)ws;
  int*   counts  = (int*)(ws + COUNTS_OFF);

  // zero counts only (partial is fully overwritten every call)
  hipMemsetAsync(counts, 0, 512, stream);

  prep_kernel<<<T_TOK / 256, 256, 0, stream>>>(sidx, counts);

  sums_kernel<<<NCHUNK * NSLICE, THREADS, 0, stream>>>(hidden, sidx, partial);

  const int totalVec4 = B_DIM * N_SLOTS * (D_DIM / 4);   // 524288
  final_kernel<<<totalVec4 / 256, 256, 0, stream>>>(memory, partial, counts, bidx, out);
}

// Round 5
// 131.674 us; speedup vs baseline: 40.2098x; 1.0024x over previous
//
#include <hip/hip_runtime.h>
#include <hip/hip_bf16.h>

// Problem constants (from reference setup_inputs)
#define T_TOK   32768
#define N_SLOTS 128
#define D_DIM   4096
#define B_DIM   4

// GEMM tiling: sums[128, 4096] = m^T[128, T] @ h[T, 4096]
#define NCHUNK  16                  // split-T
#define CTOK    (T_TOK / NCHUNK)    // 2048 tokens per block
#define KB      64                  // tokens per LDS tile (MFMA K per tile)
#define NT      (CTOK / KB)         // 32 tiles
#define WCOLS   128                 // D columns per block
#define NSLICE  (D_DIM / WCOLS)     // 32
#define THREADS 256                 // 4 waves

typedef __attribute__((ext_vector_type(8))) short short8;   // 8 bf16
typedef __attribute__((ext_vector_type(4))) float f32x4;

// ws layout: partial[NCHUNK][128][4096] f32 (32 MiB), then counts
#define PARTIAL_BYTES ((size_t)NCHUNK * N_SLOTS * D_DIM * 4)
#define COUNTS_OFF    PARTIAL_BYTES

// Barrier with LDS-only drain: do NOT drain vmcnt, so prefetched global loads
// stay in flight across the barrier (hipcc's __syncthreads drains vmcnt(0)).
#define BAR_LGKM() do { \
    asm volatile("s_waitcnt lgkmcnt(0)" ::: "memory"); \
    __builtin_amdgcn_s_barrier(); \
  } while (0)

__device__ __forceinline__ unsigned int pack_bf2(float lo, float hi) {
  // compiler lowers the casts to v_cvt_pk_bf16_f32 (RNE)
  unsigned short a = __bfloat16_as_ushort(__float2bfloat16(lo));
  unsigned short b = __bfloat16_as_ushort(__float2bfloat16(hi));
  return (unsigned int)a | ((unsigned int)b << 16);
}

// ---------------------------------------------------------------------------
// Kernel 1: counts[n] = number of tokens whose (deduped) top-K set contains n.
// ---------------------------------------------------------------------------
__global__ __launch_bounds__(256) void prep_kernel(const int* __restrict__ sidx,
                                                   int* __restrict__ counts) {
  __shared__ int cnt[N_SLOTS];
  const int tid = threadIdx.x;
  if (tid < N_SLOTS) cnt[tid] = 0;
  __syncthreads();

  const int t = blockIdx.x * 256 + tid;
  const int4 a = ((const int4*)sidx)[2 * t];
  const int4 b = ((const int4*)sidx)[2 * t + 1];
  int idx[8] = {a.x, a.y, a.z, a.w, b.x, b.y, b.z, b.w};

  #pragma unroll
  for (int k = 0; k < 8; ++k) {
    int n = idx[k];
    bool dup = false;
    #pragma unroll
    for (int j = 0; j < 8; ++j)
      if (j < k) dup |= (idx[j] == n);
    if (!dup && (unsigned)n < (unsigned)N_SLOTS) atomicAdd(&cnt[n], 1);
  }
  __syncthreads();
  if (tid < N_SLOTS && cnt[tid] > 0) atomicAdd(&counts[tid], cnt[tid]);
}

// ---------------------------------------------------------------------------
// Kernel 2: MFMA GEMM over the 512 MB h stream. No atomics anywhere.
// LDS layouts (bf16 elem index, XOR-swizzled so k-groups of 8 stay contiguous):
//   h tile: elem = col*64 + (k ^ ((col&7)<<3))   (stored as b32 k-pair words)
//   m tile: elem =   n*64 + (k ^ ((n  &7)<<3))
// m is built by zero + scatter-write of bf16 1.0 (dup writes benign => dedup free).
// Barriers drain lgkmcnt only: next-tile dwordx4 prefetch stays in flight
// across the whole compute phase instead of being force-drained at s_barrier.
// ---------------------------------------------------------------------------
__global__ __launch_bounds__(THREADS, 2) void sums_kernel(
    const float* __restrict__ hidden, const int* __restrict__ sidx,
    float* __restrict__ partial) {
  __shared__ unsigned int   h_w[2][4096];   // 16 KiB per buffer
  __shared__ unsigned short m_u[2][8192];   // 16 KiB per buffer

  const int tid = threadIdx.x;
  const int slice = blockIdx.x & (NSLICE - 1);
  const int chunk = blockIdx.x / NSLICE;
  const int d0 = slice * WCOLS;
  const int cb = chunk * CTOK;

  // staging coords: thread owns token-pair kp (k=2kp,2kp+1) x 16 cols
  const int kp = tid & 31;
  const int cg = tid >> 5;   // col group (16 cols each)

  // compute coords
  const int lane = tid & 63;
  const int wv   = tid >> 6;   // wave 0..3 -> N-tiles {2wv, 2wv+1}
  const int l15  = lane & 15;
  const int lk   = lane >> 4;  // k-group 0..3

  f32x4 acc[8][2];
  #pragma unroll
  for (int i = 0; i < 8; ++i)
    #pragma unroll
    for (int j = 0; j < 2; ++j)
      acc[i][j] = (f32x4){0.f, 0.f, 0.f, 0.f};

  float4 fa[4], fb[4];   // prefetched h: token 2kp and 2kp+1, 16 cols each
  int s0, s1;            // prefetched slot indices (flat j = tid, tid+256)

  {  // prologue: loads for tile 0
    const float* hp = hidden + (size_t)(cb + 2 * kp) * D_DIM + d0 + cg * 16;
    #pragma unroll
    for (int q = 0; q < 4; ++q) {
      fa[q] = ((const float4*)hp)[q];
      fb[q] = ((const float4*)(hp + D_DIM))[q];
    }
    s0 = sidx[cb * 8 + tid];
    s1 = sidx[cb * 8 + 256 + tid];
  }

  for (int t = 0; t < NT; ++t) {
    const int b = t & 1;
    const int cs0 = s0, cs1 = s1;   // consume prefetched indices this tile

    // ---- stage h tile: cvt f32->bf16, pack (k,k+1), b32 write (2-way free) --
    #pragma unroll
    for (int q = 0; q < 4; ++q) {
      const int colbase = cg * 16 + q * 4;
      const float ax[4] = {fa[q].x, fa[q].y, fa[q].z, fa[q].w};
      const float bx[4] = {fb[q].x, fb[q].y, fb[q].z, fb[q].w};
      #pragma unroll
      for (int c = 0; c < 4; ++c) {
        const int col = colbase + c;
        h_w[b][col * 32 + (kp ^ ((col & 7) << 2))] = pack_bf2(ax[c], bx[c]);
      }
    }

    // ---- issue next tile's global loads (stay in flight across barriers) ----
    if (t + 1 < NT) {
      const int tb = cb + (t + 1) * KB;
      const float* hp = hidden + (size_t)(tb + 2 * kp) * D_DIM + d0 + cg * 16;
      #pragma unroll
      for (int q = 0; q < 4; ++q) {
        fa[q] = ((const float4*)hp)[q];
        fb[q] = ((const float4*)(hp + D_DIM))[q];
      }
      s0 = sidx[tb * 8 + tid];
      s1 = sidx[tb * 8 + 256 + tid];
    }

    // ---- zero m tile ----
    {
      uint4* mz = (uint4*)m_u[b];
      const uint4 z = make_uint4(0, 0, 0, 0);
      #pragma unroll
      for (int i = 0; i < 4; ++i) mz[i * THREADS + tid] = z;
    }
    BAR_LGKM();   // zero visible before scatter (LDS only)

    // ---- scatter m: write bf16 1.0 at (n, token) ----
    {
      const int n0 = cs0 & (N_SLOTS - 1);
      const int t0 = tid >> 3;
      m_u[b][n0 * 64 + (t0 ^ ((n0 & 7) << 3))] = 0x3F80;
      const int n1 = cs1 & (N_SLOTS - 1);
      const int t1 = (tid + 256) >> 3;
      m_u[b][n1 * 64 + (t1 ^ ((n1 & 7) << 3))] = 0x3F80;
    }
    BAR_LGKM();   // tile staged before compute (LDS only)

    // ---- MFMA: acc += m^T(tile) @ h(tile) ----
    {
      const unsigned short* mb = m_u[b];
      const unsigned short* hb = (const unsigned short*)h_w[b];
      #pragma unroll
      for (int ks = 0; ks < 2; ++ks) {
        const int kbase = ks * 32 + lk * 8;
        const int col0 = (wv * 2) * 16 + l15;
        const int col1 = (wv * 2 + 1) * 16 + l15;
        const short8 bf0 = *(const short8*)&hb[col0 * 64 + (kbase ^ ((col0 & 7) << 3))];
        const short8 bf1 = *(const short8*)&hb[col1 * 64 + (kbase ^ ((col1 & 7) << 3))];
        #pragma unroll
        for (int mt = 0; mt < 8; ++mt) {
          const int row = mt * 16 + l15;
          const short8 af = *(const short8*)&mb[row * 64 + (kbase ^ ((row & 7) << 3))];
          acc[mt][0] = __builtin_amdgcn_mfma_f32_16x16x32_bf16(af, bf0, acc[mt][0], 0, 0, 0);
          acc[mt][1] = __builtin_amdgcn_mfma_f32_16x16x32_bf16(af, bf1, acc[mt][1], 0, 0, 0);
        }
      }
    }
  }

  // ---- flush: plain stores of this block's 128x128 tile into partial[chunk].
  //      C/D layout: col=lane&15, row=(lane>>4)*4+reg. Per store inst a wave
  //      covers 4 rows x 16 cols = 4x64B segments (full HBM-sector efficiency).
  float* pbase = partial + (size_t)chunk * N_SLOTS * D_DIM;
  #pragma unroll
  for (int mt = 0; mt < 8; ++mt)
    #pragma unroll
    for (int j = 0; j < 2; ++j) {
      const int col = d0 + (wv * 2 + j) * 16 + l15;
      #pragma unroll
      for (int r = 0; r < 4; ++r) {
        const int row = mt * 16 + lk * 4 + r;
        pbase[(size_t)row * D_DIM + col] = acc[mt][j][r];
      }
    }
}

// ---------------------------------------------------------------------------
// Kernel 3: out = memory, with row batch_idx blended:
//   counts>0 ? 0.1*(sum_c partial[c])/counts + 0.9*cur : cur
// ---------------------------------------------------------------------------
__global__ __launch_bounds__(256) void final_kernel(const float* __restrict__ memory,
                                                    const float* __restrict__ partial,
                                                    const int* __restrict__ counts,
                                                    const int* __restrict__ bidx_p,
                                                    float* __restrict__ out) {
  const size_t i = (size_t)blockIdx.x * 256 + threadIdx.x;   // float4 index
  float4 v = ((const float4*)memory)[i];
  const size_t rowLen4 = (size_t)N_SLOTS * (D_DIM / 4);
  const size_t rowStart = (size_t)(*bidx_p) * rowLen4;
  if (i >= rowStart && i < rowStart + rowLen4) {
    const size_t rel = i - rowStart;
    const int n  = (int)(rel / (D_DIM / 4));
    const int d4 = (int)(rel % (D_DIM / 4));
    const int c = counts[n];
    if (c > 0) {
      const float4* p4 = (const float4*)partial;
      float4 s = {0.f, 0.f, 0.f, 0.f};
      #pragma unroll
      for (int ch = 0; ch < NCHUNK; ++ch) {
        float4 p = p4[((size_t)ch * N_SLOTS + n) * (D_DIM / 4) + d4];
        s.x += p.x; s.y += p.y; s.z += p.z; s.w += p.w;
      }
      const float w = 0.1f / (float)c;
      v.x = s.x * w + 0.9f * v.x;
      v.y = s.y * w + 0.9f * v.y;
      v.z = s.z * w + 0.9f * v.z;
      v.w = s.w * w + 0.9f * v.w;
    }
  }
  ((float4*)out)[i] = v;
}

extern "C" void kernel_launch(void* const* d_in, const int* in_sizes, int n_in,
                              void* d_out, int out_size, void* d_ws, size_t ws_size,
                              hipStream_t stream) {
  const float* memory = (const float*)d_in[0];
  const float* hidden = (const float*)d_in[1];
  const int*   sidx   = (const int*)d_in[2];
  const int*   bidx   = (const int*)d_in[3];
  float* out = (float*)d_out;

  char* ws = (char*)d_ws;
  float* partial = (float*)ws;
  int*   counts  = (int*)(ws + COUNTS_OFF);

  // zero counts only (partial is fully overwritten every call)
  hipMemsetAsync(counts, 0, 512, stream);

  prep_kernel<<<T_TOK / 256, 256, 0, stream>>>(sidx, counts);

  sums_kernel<<<NCHUNK * NSLICE, THREADS, 0, stream>>>(hidden, sidx, partial);

  const int totalVec4 = B_DIM * N_SLOTS * (D_DIM / 4);   // 524288
  final_kernel<<<totalVec4 / 256, 256, 0, stream>>>(memory, partial, counts, bidx, out);
}